// Round 2
// baseline (471.141 us; speedup 1.0000x reference)
//
#include <hip/hip_runtime.h>
#include <stdint.h>

#define B_    4
#define CIN   32
#define NN    1024
#define SS    32
#define COUT  64
#define CSP   64
#define EPSV  1e-5f

// ---------- graph prep ----------
// Detect whether edge_index arrived as int64 (odd 32-bit words all zero) or int32.
__global__ void detect_kernel(const int* __restrict__ ei, int* __restrict__ flag) {
    if (threadIdx.x == 0) {
        int nz = 0;
        for (int i = 1; i < 257; i += 2) nz |= ei[i];
        *flag = (nz == 0) ? 1 : 0;   // 1 => int64 layout
    }
}

__global__ void deg_count_kernel(const int* __restrict__ ei, int E,
                                 const int* __restrict__ flag, int* __restrict__ deg) {
    int e = blockIdx.x * 256 + threadIdx.x;
    int i64 = *flag;
    if (e < E) {
        int d = i64 ? ei[2 * (E + e)] : ei[E + e];
        atomicAdd(&deg[d], 1);
    }
}

__global__ __launch_bounds__(1024) void scan_kernel(
    const int* __restrict__ deg, int* __restrict__ row_ptr, float* __restrict__ dinv) {
    __shared__ int sb[NN];
    int t = threadIdx.x;
    int v = deg[t];
    sb[t] = v;
    __syncthreads();
    for (int off = 1; off < NN; off <<= 1) {
        int tmp = (t >= off) ? sb[t - off] : 0;
        __syncthreads();
        sb[t] += tmp;
        __syncthreads();
    }
    row_ptr[t] = sb[t] - v;                 // exclusive scan
    if (t == NN - 1) row_ptr[NN] = sb[t];
    dinv[t] = rsqrtf((float)(v + 1));       // +1 self-loop
}

__global__ void csr_fill_kernel(const int* __restrict__ ei, int E,
                                const int* __restrict__ flag,
                                const int* __restrict__ row_ptr, int* __restrict__ cursor,
                                int* __restrict__ col) {
    int e = blockIdx.x * 256 + threadIdx.x;
    int i64 = *flag;
    if (e < E) {
        int s = i64 ? ei[2 * e] : ei[e];
        int d = i64 ? ei[2 * (E + e)] : ei[E + e];
        int pos = atomicAdd(&cursor[d], 1);
        col[row_ptr[d] + pos] = s;
    }
}

// ---------- temporal conv1: x[B,Cin,N,S] -> h_pre[B*N,Cout,S] (pre-BN) ----------
__global__ __launch_bounds__(256) void conv1_kernel(
    const float* __restrict__ x, const float* __restrict__ W1,
    const float* __restrict__ b1, float* __restrict__ h_pre) {
    __shared__ __align__(16) float xs[CIN][36];     // halo at [0] and [33]
    __shared__ float w1l[COUT * 97];                // stride 97: conflict-free
    int t = threadIdx.x;
    int bn = blockIdx.x;
    int b = bn >> 10, n = bn & (NN - 1);
    {
        int cin = t >> 3, s4 = (t & 7) * 4;
        float4 v = *(const float4*)(x + (((size_t)b * CIN + cin) * NN + n) * SS + s4);
        xs[cin][s4 + 1] = v.x; xs[cin][s4 + 2] = v.y;
        xs[cin][s4 + 3] = v.z; xs[cin][s4 + 4] = v.w;
    }
    if (t < 64) xs[t & 31][(t < 32) ? 0 : 33] = 0.f;
#pragma unroll
    for (int i = 0; i < 6; i++) {
        int lin = (i * 256 + t) * 4;                // rows of 96 (96%4==0: no row cross)
        int cout = lin / 96, r = lin - cout * 96;
        float4 v = *(const float4*)(W1 + lin);
        float* dst = &w1l[cout * 97 + r];
        dst[0] = v.x; dst[1] = v.y; dst[2] = v.z; dst[3] = v.w;
    }
    __syncthreads();
    int cout = t >> 2, s0 = (t & 3) * 8;
    float y[8];
    float bb = b1[cout];
#pragma unroll
    for (int j = 0; j < 8; j++) y[j] = bb;
    const float* wrow = &w1l[cout * 97];
#pragma unroll 4
    for (int cin = 0; cin < CIN; cin++) {
        float w0 = wrow[cin * 3], w1v = wrow[cin * 3 + 1], w2v = wrow[cin * 3 + 2];
        const float* xr = &xs[cin][0];
        float4 xa = *(const float4*)(xr + s0);
        float4 xb = *(const float4*)(xr + s0 + 4);
        float4 xc = *(const float4*)(xr + s0 + 8);
        float xv[12] = {xa.x, xa.y, xa.z, xa.w, xb.x, xb.y, xb.z, xb.w, xc.x, xc.y, xc.z, xc.w};
#pragma unroll
        for (int j = 0; j < 8; j++) y[j] += xv[j] * w0 + xv[j + 1] * w1v + xv[j + 2] * w2v;
    }
    float* op = h_pre + (size_t)bn * COUT * SS + cout * SS + s0;
    float4 o0 = {y[0], y[1], y[2], y[3]}, o1 = {y[4], y[5], y[6], y[7]};
    *(float4*)op = o0; *(float4*)(op + 4) = o1;
}

// ---------- per-channel stats over [B*N, C, S] (axes 0,2) ----------
__global__ __launch_bounds__(256) void bn_stats_kernel(
    const float* __restrict__ h, float* __restrict__ gsum, float* __restrict__ gss) {
    int c = blockIdx.x >> 3, chunk = blockIdx.x & 7;    // 64 ch x 8 chunks of 512 bn
    float sum = 0.f, ss = 0.f;
    const float* base = h + (size_t)chunk * 512 * COUT * SS + (size_t)c * SS;
#pragma unroll 4
    for (int i = 0; i < 16; i++) {
        int chk = i * 256 + threadIdx.x;
        int bnl = chk >> 3, sc = (chk & 7) * 4;
        float4 v = *(const float4*)(base + (size_t)bnl * COUT * SS + sc);
        sum += v.x + v.y + v.z + v.w;
        ss += v.x * v.x + v.y * v.y + v.z * v.z + v.w * v.w;
    }
#pragma unroll
    for (int o = 32; o > 0; o >>= 1) { sum += __shfl_down(sum, o); ss += __shfl_down(ss, o); }
    __shared__ float wsum[4], wss[4];
    int wid = threadIdx.x >> 6;
    if ((threadIdx.x & 63) == 0) { wsum[wid] = sum; wss[wid] = ss; }
    __syncthreads();
    if (threadIdx.x == 0) {
        atomicAdd(&gsum[c], wsum[0] + wsum[1] + wsum[2] + wsum[3]);
        atomicAdd(&gss[c],  wss[0] + wss[1] + wss[2] + wss[3]);
    }
}

__global__ void bn_finalize_kernel(const float* __restrict__ sum, const float* __restrict__ ss,
                                   const float* __restrict__ g, const float* __restrict__ be,
                                   float* __restrict__ scale, float* __restrict__ shift,
                                   float invM) {
    int c = threadIdx.x;    // 64
    float m = sum[c] * invM;
    float v = ss[c] * invM - m * m;
    float sc = g[c] * rsqrtf(v + EPSV);
    scale[c] = sc;
    shift[c] = be[c] - m * sc;
}

// ---------- BN1 apply + ReLU + (h · Wg) -> hw[B,S,N,Csp] ----------
__global__ __launch_bounds__(256) void bn1_gemm_kernel(
    const float* __restrict__ h_pre, const float* __restrict__ scale1,
    const float* __restrict__ shift1, const float* __restrict__ Wg,
    float* __restrict__ hw) {
    __shared__ __align__(16) float hs[COUT][36];
    __shared__ float wgl[COUT * CSP];
    int t = threadIdx.x;
    int bn = blockIdx.x;
    int b = bn >> 10, n = bn & (NN - 1);
    {
        const float* p = h_pre + (size_t)bn * COUT * SS + t * 8;
        float4 a = *(const float4*)p, b4 = *(const float4*)(p + 4);
        int c = t >> 2, s = (t & 3) * 8;
        float sc = scale1[c], sh = shift1[c];
        float f[8] = {a.x, a.y, a.z, a.w, b4.x, b4.y, b4.z, b4.w};
#pragma unroll
        for (int j = 0; j < 8; j++) hs[c][s + j] = fmaxf(sc * f[j] + sh, 0.f);
    }
#pragma unroll
    for (int i = 0; i < 4; i++) {
        int lin = (i * 256 + t) * 4;
        float4 v = *(const float4*)(Wg + lin);
        wgl[lin] = v.x; wgl[lin + 1] = v.y; wgl[lin + 2] = v.z; wgl[lin + 3] = v.w;
    }
    __syncthreads();
    int d = t & 63, s0 = (t >> 6) * 8;      // s0 wave-uniform
    float acc[8];
#pragma unroll
    for (int j = 0; j < 8; j++) acc[j] = 0.f;
#pragma unroll 4
    for (int c = 0; c < COUT; c++) {
        float w = wgl[c * 64 + d];
        float4 ha = *(const float4*)&hs[c][s0];
        float4 hb = *(const float4*)&hs[c][s0 + 4];
        acc[0] += ha.x * w; acc[1] += ha.y * w; acc[2] += ha.z * w; acc[3] += ha.w * w;
        acc[4] += hb.x * w; acc[5] += hb.y * w; acc[6] += hb.z * w; acc[7] += hb.w * w;
    }
#pragma unroll
    for (int j = 0; j < 8; j++) {
        hw[((size_t)(b * SS + s0 + j) * NN + n) * CSP + d] = acc[j];
    }
}

// ---------- GCN aggregate (CSR gather) + BN2 partial stats ----------
__global__ __launch_bounds__(256) void gcn_kernel(
    const float* __restrict__ hw, const int* __restrict__ row_ptr,
    const int* __restrict__ col, const float* __restrict__ dinv,
    const float* __restrict__ bg, float* __restrict__ agg,
    float* __restrict__ sum2, float* __restrict__ ss2) {
    int bs = blockIdx.x >> 5, ng = blockIdx.x & 31;     // 128 (b,s) x 32 node-chunks
    int d = threadIdx.x & 63, nl = threadIdx.x >> 6;
    const float* hwb = hw + (size_t)bs * NN * CSP;
    float* aggb = agg + (size_t)bs * NN * CSP;
    float bgf = bg[d];
    float sum = 0.f, ss = 0.f;
    for (int i = 0; i < 8; i++) {
        int n = ng * 32 + i * 4 + nl;                   // wave-uniform n
        int r0 = row_ptr[n], r1 = row_ptr[n + 1];
        float dn = dinv[n];
        float acc = dn * hwb[(size_t)n * CSP + d];      // self-loop
        for (int r = r0; r < r1; r++) {
            int srcn = col[r];
            acc += dinv[srcn] * hwb[(size_t)srcn * CSP + d];
        }
        float v = dn * acc + bgf;
        aggb[(size_t)n * CSP + d] = v;
        sum += v; ss += v * v;
    }
    __shared__ float ls[4][64], lq[4][64];
    ls[nl][d] = sum; lq[nl][d] = ss;
    __syncthreads();
    if (threadIdx.x < 64) {
        float s = ls[0][d] + ls[1][d] + ls[2][d] + ls[3][d];
        float q = lq[0][d] + lq[1][d] + lq[2][d] + lq[3][d];
        atomicAdd(&sum2[bs * 64 + d], s);
        atomicAdd(&ss2[bs * 64 + d], q);
    }
}

__global__ void bn2_finalize_kernel(const float* __restrict__ sum2, const float* __restrict__ ss2,
                                    const float* __restrict__ gs, const float* __restrict__ bes,
                                    float* __restrict__ scale2, float* __restrict__ shift2) {
    int idx = blockIdx.x * 256 + threadIdx.x;   // 8192 = B*S*Csp
    int d = idx & 63;
    float m = sum2[idx] * (1.f / NN);
    float v = ss2[idx] * (1.f / NN) - m * m;
    float sc = gs[d] * rsqrtf(v + EPSV);
    scale2[idx] = sc;
    shift2[idx] = bes[d] - m * sc;
}

// ---------- BN2 apply + ReLU + temporal conv2 -> h2_pre[B*N,Cout,S] ----------
__global__ __launch_bounds__(256) void conv2_kernel(
    const float* __restrict__ agg, const float* __restrict__ scale2,
    const float* __restrict__ shift2, const float* __restrict__ W2,
    const float* __restrict__ b2, float* __restrict__ h2_pre) {
    __shared__ __align__(16) float ts[CSP][36];     // halo at [0] and [33]
    __shared__ float w2l[COUT * 193];               // stride 193: conflict-free
    int t = threadIdx.x;
    int bn = blockIdx.x;
    int b = bn >> 10, n = bn & (NN - 1);
#pragma unroll
    for (int i = 0; i < 8; i++) {
        int lin = i * 256 + t;
        int s = lin >> 6, cin = lin & 63;
        int bsi = b * SS + s;
        float v = agg[((size_t)bsi * NN + n) * CSP + cin];
        v = fmaxf(scale2[bsi * 64 + cin] * v + shift2[bsi * 64 + cin], 0.f);
        ts[cin][s + 1] = v;
    }
    if (t < 128) ts[t & 63][(t < 64) ? 0 : 33] = 0.f;
#pragma unroll
    for (int i = 0; i < 12; i++) {
        int lin = (i * 256 + t) * 4;                // rows of 192 (192%4==0)
        int cout = lin / 192, r = lin - cout * 192;
        float4 v = *(const float4*)(W2 + lin);
        float* dst = &w2l[cout * 193 + r];
        dst[0] = v.x; dst[1] = v.y; dst[2] = v.z; dst[3] = v.w;
    }
    __syncthreads();
    int cout = t >> 2, s0 = (t & 3) * 8;
    float y[8];
    float bb = b2[cout];
#pragma unroll
    for (int j = 0; j < 8; j++) y[j] = bb;
    const float* wrow = &w2l[cout * 193];
#pragma unroll 4
    for (int cin = 0; cin < CSP; cin++) {
        float w0 = wrow[cin * 3], w1v = wrow[cin * 3 + 1], w2v = wrow[cin * 3 + 2];
        const float* xr = &ts[cin][0];
        float4 xa = *(const float4*)(xr + s0);
        float4 xb = *(const float4*)(xr + s0 + 4);
        float4 xc = *(const float4*)(xr + s0 + 8);
        float xv[12] = {xa.x, xa.y, xa.z, xa.w, xb.x, xb.y, xb.z, xb.w, xc.x, xc.y, xc.z, xc.w};
#pragma unroll
        for (int j = 0; j < 8; j++) y[j] += xv[j] * w0 + xv[j + 1] * w1v + xv[j + 2] * w2v;
    }
    float* op = h2_pre + (size_t)bn * COUT * SS + cout * SS + s0;
    float4 o0 = {y[0], y[1], y[2], y[3]}, o1 = {y[4], y[5], y[6], y[7]};
    *(float4*)op = o0; *(float4*)(op + 4) = o1;
}

// ---------- final: BN3+ReLU + residual 1x1 conv + ReLU, write [B,Cout,N,S] ----------
__global__ __launch_bounds__(256) void final_kernel(
    const float* __restrict__ x, const float* __restrict__ Wres,
    const float* __restrict__ bres, const float* __restrict__ h2_pre,
    const float* __restrict__ scale3, const float* __restrict__ shift3,
    float* __restrict__ out) {
    __shared__ __align__(16) float xs[CIN][36];
    __shared__ float wrl[COUT * 33];                // stride 33: conflict-free
    int t = threadIdx.x;
    int bn = blockIdx.x;
    int b = bn >> 10, n = bn & (NN - 1);
    {
        int cin = t >> 3, s4 = (t & 7) * 4;         // (cin*36+s4)%4==0: aligned
        *(float4*)&xs[cin][s4] =
            *(const float4*)(x + (((size_t)b * CIN + cin) * NN + n) * SS + s4);
    }
#pragma unroll
    for (int i = 0; i < 2; i++) {
        int lin = (i * 256 + t) * 4;                // rows of 32 (32%4==0)
        int cw = lin >> 5, c0 = lin & 31;
        float4 v = *(const float4*)(Wres + lin);
        float* dst = &wrl[cw * 33 + c0];
        dst[0] = v.x; dst[1] = v.y; dst[2] = v.z; dst[3] = v.w;
    }
    __syncthreads();
    int cout = t >> 2, s0 = (t & 3) * 8;
    float res[8];
    float bb = bres[cout];
#pragma unroll
    for (int j = 0; j < 8; j++) res[j] = bb;
    const float* wrow = &wrl[cout * 33];
#pragma unroll 4
    for (int cin = 0; cin < CIN; cin++) {
        float w = wrow[cin];
        float4 xa = *(const float4*)&xs[cin][s0];
        float4 xb = *(const float4*)&xs[cin][s0 + 4];
        res[0] += xa.x * w; res[1] += xa.y * w; res[2] += xa.z * w; res[3] += xa.w * w;
        res[4] += xb.x * w; res[5] += xb.y * w; res[6] += xb.z * w; res[7] += xb.w * w;
    }
    const float* hp = h2_pre + (size_t)bn * COUT * SS + cout * SS + s0;
    float4 h0 = *(const float4*)hp, h1 = *(const float4*)(hp + 4);
    float h2[8] = {h0.x, h0.y, h0.z, h0.w, h1.x, h1.y, h1.z, h1.w};
    float sc = scale3[cout], sh = shift3[cout];
    float o[8];
#pragma unroll
    for (int j = 0; j < 8; j++) {
        float hv = fmaxf(sc * h2[j] + sh, 0.f);
        o[j] = fmaxf(hv + res[j], 0.f);
    }
    float* op = out + (((size_t)b * COUT + cout) * NN + n) * SS + s0;
    float4 o0 = {o[0], o[1], o[2], o[3]}, o1 = {o[4], o[5], o[6], o[7]};
    *(float4*)op = o0; *(float4*)(op + 4) = o1;
}

// ---------- host ----------
extern "C" void kernel_launch(void* const* d_in, const int* in_sizes, int n_in,
                              void* d_out, int out_size, void* d_ws, size_t ws_size,
                              hipStream_t stream) {
    const float* x    = (const float*)d_in[0];
    const int*   ei   = (const int*)  d_in[1];
    const float* W1   = (const float*)d_in[2];
    const float* b1   = (const float*)d_in[3];
    const float* g1   = (const float*)d_in[4];
    const float* be1  = (const float*)d_in[5];
    const float* Wg   = (const float*)d_in[6];
    const float* bg   = (const float*)d_in[7];
    const float* gs   = (const float*)d_in[8];
    const float* bes  = (const float*)d_in[9];
    const float* W2   = (const float*)d_in[10];
    const float* b2   = (const float*)d_in[11];
    const float* g2   = (const float*)d_in[12];
    const float* be2  = (const float*)d_in[13];
    const float* Wres = (const float*)d_in[14];
    const float* bres = (const float*)d_in[15];
    float* out = (float*)d_out;
    int E = in_sizes[1] / 2;

    char* ws = (char*)d_ws;
    // zeroed region: [0, 74752)
    int*   deg    = (int*)  (ws + 0);            // 4096 B
    int*   cursor = (int*)  (ws + 4096);         // 4096 B
    float* sum1   = (float*)(ws + 8192);         // 256 B each
    float* ssq1   = (float*)(ws + 8448);
    float* sum3   = (float*)(ws + 8704);
    float* ssq3   = (float*)(ws + 8960);
    float* sum2   = (float*)(ws + 9216);         // 32768 B
    float* ssq2   = (float*)(ws + 41984);        // 32768 B -> ends 74752
    int*   row_ptr= (int*)  (ws + 74752);        // 4100 B
    int*   flag   = (int*)  (ws + 78912);        // 4 B
    int*   col    = (int*)  (ws + 79104);        // 65536 B
    float* dinv   = (float*)(ws + 144640);       // 4096 B
    float* scale1 = (float*)(ws + 148736);
    float* shift1 = (float*)(ws + 148992);
    float* scale3 = (float*)(ws + 149248);
    float* shift3 = (float*)(ws + 149504);
    float* scale2 = (float*)(ws + 149760);       // 32768 B
    float* shift2 = (float*)(ws + 182528);       // 32768 B -> ends 215296
    float* bigA   = (float*)(ws + 215296);       // 33.55 MB: hw, then h2_pre
    // d_out doubles as scratch: h_pre (conv1 out), then agg (gcn out).
    float* h_pre  = out;
    float* agg    = out;

    hipMemsetAsync(ws, 0, 74752, stream);
    detect_kernel<<<1, 64, 0, stream>>>(ei, flag);
    int egrid = (E + 255) / 256;
    deg_count_kernel<<<egrid, 256, 0, stream>>>(ei, E, flag, deg);
    scan_kernel<<<1, NN, 0, stream>>>(deg, row_ptr, dinv);
    csr_fill_kernel<<<egrid, 256, 0, stream>>>(ei, E, flag, row_ptr, cursor, col);

    conv1_kernel<<<B_ * NN, 256, 0, stream>>>(x, W1, b1, h_pre);
    bn_stats_kernel<<<512, 256, 0, stream>>>(h_pre, sum1, ssq1);
    bn_finalize_kernel<<<1, 64, 0, stream>>>(sum1, ssq1, g1, be1, scale1, shift1,
                                             1.f / (B_ * NN * SS));
    bn1_gemm_kernel<<<B_ * NN, 256, 0, stream>>>(h_pre, scale1, shift1, Wg, bigA);
    gcn_kernel<<<B_ * SS * (NN / 32), 256, 0, stream>>>(bigA, row_ptr, col, dinv, bg, agg,
                                                        sum2, ssq2);
    bn2_finalize_kernel<<<32, 256, 0, stream>>>(sum2, ssq2, gs, bes, scale2, shift2);
    conv2_kernel<<<B_ * NN, 256, 0, stream>>>(agg, scale2, shift2, W2, b2, bigA);
    bn_stats_kernel<<<512, 256, 0, stream>>>(bigA, sum3, ssq3);
    bn_finalize_kernel<<<1, 64, 0, stream>>>(sum3, ssq3, g2, be2, scale3, shift3,
                                             1.f / (B_ * NN * SS));
    final_kernel<<<B_ * NN, 256, 0, stream>>>(x, Wres, bres, bigA, scale3, shift3, out);
}

// Round 3
// 344.941 us; speedup vs baseline: 1.3659x; 1.3659x over previous
//
#include <hip/hip_runtime.h>
#include <stdint.h>

#define B_    4
#define CIN   32
#define NN    1024
#define SS    32
#define COUT  64
#define CSP   64
#define EPSV  1e-5f

// ---------- graph prep ----------
// Detect whether edge_index arrived as int64 (odd 32-bit words all zero) or int32.
__global__ void detect_kernel(const int* __restrict__ ei, int* __restrict__ flag) {
    if (threadIdx.x == 0) {
        int nz = 0;
        for (int i = 1; i < 257; i += 2) nz |= ei[i];
        *flag = (nz == 0) ? 1 : 0;   // 1 => int64 layout
    }
}

__global__ void deg_count_kernel(const int* __restrict__ ei, int E,
                                 const int* __restrict__ flag, int* __restrict__ deg) {
    int e = blockIdx.x * 256 + threadIdx.x;
    int i64 = *flag;
    if (e < E) {
        int d = i64 ? ei[2 * (E + e)] : ei[E + e];
        atomicAdd(&deg[d], 1);
    }
}

__global__ __launch_bounds__(1024) void scan_kernel(
    const int* __restrict__ deg, int* __restrict__ row_ptr, float* __restrict__ dinv) {
    __shared__ int sb[NN];
    int t = threadIdx.x;
    int v = deg[t];
    sb[t] = v;
    __syncthreads();
    for (int off = 1; off < NN; off <<= 1) {
        int tmp = (t >= off) ? sb[t - off] : 0;
        __syncthreads();
        sb[t] += tmp;
        __syncthreads();
    }
    row_ptr[t] = sb[t] - v;                 // exclusive scan
    if (t == NN - 1) row_ptr[NN] = sb[t];
    dinv[t] = rsqrtf((float)(v + 1));       // +1 self-loop
}

// Writes packed edge descriptors: {srcn*64 (row offset in hw slice), dinv[srcn]}
__global__ void csr_fill_kernel(const int* __restrict__ ei, int E,
                                const int* __restrict__ flag,
                                const int* __restrict__ row_ptr, int* __restrict__ cursor,
                                const float* __restrict__ dinv, int2* __restrict__ edata) {
    int e = blockIdx.x * 256 + threadIdx.x;
    int i64 = *flag;
    if (e < E) {
        int s = i64 ? ei[2 * e] : ei[e];
        int d = i64 ? ei[2 * (E + e)] : ei[E + e];
        int pos = atomicAdd(&cursor[d], 1);
        edata[row_ptr[d] + pos] = make_int2(s * CSP, __float_as_int(dinv[s]));
    }
}

// ---------- temporal conv1 (8 tiles/block) + fused BN1 partial stats ----------
__global__ __launch_bounds__(256) void conv1_kernel(
    const float* __restrict__ x, const float* __restrict__ W1,
    const float* __restrict__ b1, float* __restrict__ h_pre,
    float* __restrict__ psum, float* __restrict__ pss) {
    __shared__ __align__(16) float xs[CIN][36];     // halo at [0] and [33]
    __shared__ float w1l[COUT * 97];                // stride 97: conflict-free
    int t = threadIdx.x;
    int grp = blockIdx.x;                           // 512 groups of 8 n's
    int b = grp >> 7, n0 = (grp & 127) * 8;
#pragma unroll
    for (int i = 0; i < 6; i++) {
        int lin = (i * 256 + t) * 4;                // rows of 96 (96%4==0)
        int cout = lin / 96, r = lin - cout * 96;
        float4 v = *(const float4*)(W1 + lin);
        float* dst = &w1l[cout * 97 + r];
        dst[0] = v.x; dst[1] = v.y; dst[2] = v.z; dst[3] = v.w;
    }
    if (t < 64) xs[t & 31][(t < 32) ? 0 : 33] = 0.f;    // halo, written once
    int cout = t >> 2, s0 = (t & 3) * 8;
    float bb = b1[cout];
    const float* wrow = &w1l[cout * 97];
    float accS = 0.f, accQ = 0.f;
    for (int g = 0; g < 8; g++) {
        int n = n0 + g;
        __syncthreads();                            // xs free from prev tile
        {
            int cin = t >> 3, s4 = (t & 7) * 4;
            float4 v = *(const float4*)(x + (((size_t)b * CIN + cin) * NN + n) * SS + s4);
            xs[cin][s4 + 1] = v.x; xs[cin][s4 + 2] = v.y;
            xs[cin][s4 + 3] = v.z; xs[cin][s4 + 4] = v.w;
        }
        __syncthreads();
        float y[8];
#pragma unroll
        for (int j = 0; j < 8; j++) y[j] = bb;
#pragma unroll 4
        for (int cin = 0; cin < CIN; cin++) {
            float w0 = wrow[cin * 3], w1v = wrow[cin * 3 + 1], w2v = wrow[cin * 3 + 2];
            const float* xr = &xs[cin][0];
            float4 xa = *(const float4*)(xr + s0);
            float4 xb = *(const float4*)(xr + s0 + 4);
            float4 xc = *(const float4*)(xr + s0 + 8);
            float xv[12] = {xa.x, xa.y, xa.z, xa.w, xb.x, xb.y, xb.z, xb.w,
                            xc.x, xc.y, xc.z, xc.w};
#pragma unroll
            for (int j = 0; j < 8; j++) y[j] += xv[j] * w0 + xv[j + 1] * w1v + xv[j + 2] * w2v;
        }
        float* op = h_pre + (size_t)(b * NN + n) * COUT * SS + cout * SS + s0;
        float4 o0 = {y[0], y[1], y[2], y[3]}, o1 = {y[4], y[5], y[6], y[7]};
        *(float4*)op = o0; *(float4*)(op + 4) = o1;
        // partial stats (pre-BN h): quad-reduce s0 lanes sharing cout
        float s = 0.f, q = 0.f;
#pragma unroll
        for (int j = 0; j < 8; j++) { s += y[j]; q += y[j] * y[j]; }
        s += __shfl_down(s, 1); s += __shfl_down(s, 2);
        q += __shfl_down(q, 1); q += __shfl_down(q, 2);
        accS += s; accQ += q;                       // valid on lanes (t&3)==0
    }
    if ((t & 3) == 0) {
        psum[cout * 512 + grp] = accS;
        pss[cout * 512 + grp] = accQ;
    }
}

// ---------- reduce per-block partials -> scale/shift ----------
__global__ void bn_reduce_kernel(const float* __restrict__ psum, const float* __restrict__ pss,
                                 const float* __restrict__ g, const float* __restrict__ be,
                                 float* __restrict__ scale, float* __restrict__ shift,
                                 float invM) {
    int c = blockIdx.x, t = threadIdx.x;    // 64 blocks x 256 threads
    float s = psum[c * 512 + t] + psum[c * 512 + 256 + t];
    float q = pss[c * 512 + t] + pss[c * 512 + 256 + t];
#pragma unroll
    for (int o = 32; o > 0; o >>= 1) { s += __shfl_down(s, o); q += __shfl_down(q, o); }
    __shared__ float ws_[4], wq_[4];
    if ((t & 63) == 0) { ws_[t >> 6] = s; wq_[t >> 6] = q; }
    __syncthreads();
    if (t == 0) {
        float S = ws_[0] + ws_[1] + ws_[2] + ws_[3];
        float Q = wq_[0] + wq_[1] + wq_[2] + wq_[3];
        float m = S * invM, v = Q * invM - m * m;
        float sc = g[c] * rsqrtf(v + EPSV);
        scale[c] = sc;
        shift[c] = be[c] - m * sc;
    }
}

// ---------- BN1 apply + ReLU + (h · Wg) -> hw[B,S,N,Csp], 8 tiles/block ----------
__global__ __launch_bounds__(256) void bn1_gemm_kernel(
    const float* __restrict__ h_pre, const float* __restrict__ scale1,
    const float* __restrict__ shift1, const float* __restrict__ Wg,
    float* __restrict__ hw) {
    __shared__ __align__(16) float hs[COUT][36];
    __shared__ float wgl[COUT * CSP];
    int t = threadIdx.x;
    int grp = blockIdx.x;
    int b = grp >> 7, n0 = (grp & 127) * 8;
#pragma unroll
    for (int i = 0; i < 4; i++) {
        int lin = (i * 256 + t) * 4;
        float4 v = *(const float4*)(Wg + lin);
        wgl[lin] = v.x; wgl[lin + 1] = v.y; wgl[lin + 2] = v.z; wgl[lin + 3] = v.w;
    }
    int cs = t >> 2, ssi = (t & 3) * 8;     // staging role
    float sc1 = scale1[cs], sh1 = shift1[cs];
    int d = t & 63, sO = (t >> 6) * 8;      // compute role (sO wave-uniform)
    for (int g = 0; g < 8; g++) {
        int n = n0 + g;
        __syncthreads();
        {
            const float* p = h_pre + (size_t)(b * NN + n) * COUT * SS + t * 8;
            float4 a = *(const float4*)p, b4 = *(const float4*)(p + 4);
            float f[8] = {a.x, a.y, a.z, a.w, b4.x, b4.y, b4.z, b4.w};
#pragma unroll
            for (int j = 0; j < 8; j++) hs[cs][ssi + j] = fmaxf(sc1 * f[j] + sh1, 0.f);
        }
        __syncthreads();
        float acc[8];
#pragma unroll
        for (int j = 0; j < 8; j++) acc[j] = 0.f;
#pragma unroll 4
        for (int c = 0; c < COUT; c++) {
            float w = wgl[c * 64 + d];
            float4 ha = *(const float4*)&hs[c][sO];
            float4 hb = *(const float4*)&hs[c][sO + 4];
            acc[0] += ha.x * w; acc[1] += ha.y * w; acc[2] += ha.z * w; acc[3] += ha.w * w;
            acc[4] += hb.x * w; acc[5] += hb.y * w; acc[6] += hb.z * w; acc[7] += hb.w * w;
        }
#pragma unroll
        for (int j = 0; j < 8; j++) {
            hw[((size_t)(b * SS + sO + j) * NN + n) * CSP + d] = acc[j];
        }
    }
}

// ---------- GCN aggregate (CSR gather, XCD-swizzled) + BN2 partial stats ----------
__global__ __launch_bounds__(256) void gcn_kernel(
    const float* __restrict__ hw, const int* __restrict__ row_ptr,
    const int2* __restrict__ edata, const float* __restrict__ dinv,
    const float* __restrict__ bg, float* __restrict__ agg,
    float* __restrict__ sum2, float* __restrict__ ss2) {
    // XCD swizzle: all 32 node-chunks of one (b,s) slice land on one XCD
    // (round-robin heuristic: XCD = blockIdx % 8).
    int xcd = blockIdx.x & 7, j = blockIdx.x >> 3;
    int bs = xcd * 16 + (j >> 5), ng = j & 31;
    int d = threadIdx.x & 63, nl = threadIdx.x >> 6;
    const float* hwb = hw + (size_t)bs * NN * CSP;
    float* aggb = agg + (size_t)bs * NN * CSP;
    float bgf = bg[d];
    float sum = 0.f, ss = 0.f;
    for (int i = 0; i < 8; i++) {
        int n = ng * 32 + i * 4 + nl;                   // wave-uniform n
        int r0 = row_ptr[n], r1 = row_ptr[n + 1];
        float dn = dinv[n];
        float a0 = dn * hwb[n * CSP + d];               // self-loop
        float a1 = 0.f, a2 = 0.f, a3 = 0.f;
        int r = r0;
        for (; r + 4 <= r1; r += 4) {                   // 4 independent chains
            int2 e0 = edata[r], e1 = edata[r + 1], e2 = edata[r + 2], e3 = edata[r + 3];
            a0 += __int_as_float(e0.y) * hwb[e0.x + d];
            a1 += __int_as_float(e1.y) * hwb[e1.x + d];
            a2 += __int_as_float(e2.y) * hwb[e2.x + d];
            a3 += __int_as_float(e3.y) * hwb[e3.x + d];
        }
        for (; r < r1; r++) {
            int2 e = edata[r];
            a0 += __int_as_float(e.y) * hwb[e.x + d];
        }
        float v = dn * ((a0 + a1) + (a2 + a3)) + bgf;
        aggb[n * CSP + d] = v;
        sum += v; ss += v * v;
    }
    __shared__ float ls[4][64], lq[4][64];
    ls[nl][d] = sum; lq[nl][d] = ss;
    __syncthreads();
    if (threadIdx.x < 64) {
        float s = ls[0][d] + ls[1][d] + ls[2][d] + ls[3][d];
        float q = lq[0][d] + lq[1][d] + lq[2][d] + lq[3][d];
        atomicAdd(&sum2[bs * 64 + d], s);
        atomicAdd(&ss2[bs * 64 + d], q);
    }
}

__global__ void bn2_finalize_kernel(const float* __restrict__ sum2, const float* __restrict__ ss2,
                                    const float* __restrict__ gs, const float* __restrict__ bes,
                                    float* __restrict__ scale2, float* __restrict__ shift2) {
    int idx = blockIdx.x * 256 + threadIdx.x;   // 8192 = B*S*Csp
    int d = idx & 63;
    float m = sum2[idx] * (1.f / NN);
    float v = ss2[idx] * (1.f / NN) - m * m;
    float sc = gs[d] * rsqrtf(v + EPSV);
    scale2[idx] = sc;
    shift2[idx] = bes[d] - m * sc;
}

// ---------- BN2 apply + ReLU + temporal conv2 (8 tiles/block) + BN3 partials ----------
__global__ __launch_bounds__(256) void conv2_kernel(
    const float* __restrict__ agg, const float* __restrict__ scale2,
    const float* __restrict__ shift2, const float* __restrict__ W2,
    const float* __restrict__ b2, float* __restrict__ h2_pre,
    float* __restrict__ psum, float* __restrict__ pss) {
    __shared__ __align__(16) float ts[CSP][36];     // halo at [0] and [33]
    __shared__ float w2l[COUT * 193];               // stride 193: conflict-free
    int t = threadIdx.x;
    int grp = blockIdx.x;
    int b = grp >> 7, n0 = (grp & 127) * 8;
#pragma unroll
    for (int i = 0; i < 12; i++) {
        int lin = (i * 256 + t) * 4;                // rows of 192 (192%4==0)
        int cout = lin / 192, r = lin - cout * 192;
        float4 v = *(const float4*)(W2 + lin);
        float* dst = &w2l[cout * 193 + r];
        dst[0] = v.x; dst[1] = v.y; dst[2] = v.z; dst[3] = v.w;
    }
    if (t < 128) ts[t & 63][(t < 64) ? 0 : 33] = 0.f;
    int cout = t >> 2, s0 = (t & 3) * 8;
    float bb = b2[cout];
    const float* wrow = &w2l[cout * 193];
    float accS = 0.f, accQ = 0.f;
    for (int g = 0; g < 8; g++) {
        int n = n0 + g;
        __syncthreads();
#pragma unroll
        for (int i = 0; i < 8; i++) {
            int lin = i * 256 + t;
            int s = lin >> 6, cin = lin & 63;
            int bsi = b * SS + s;
            float v = agg[((size_t)bsi * NN + n) * CSP + cin];
            v = fmaxf(scale2[bsi * 64 + cin] * v + shift2[bsi * 64 + cin], 0.f);
            ts[cin][s + 1] = v;
        }
        __syncthreads();
        float y[8];
#pragma unroll
        for (int j = 0; j < 8; j++) y[j] = bb;
#pragma unroll 4
        for (int cin = 0; cin < CSP; cin++) {
            float w0 = wrow[cin * 3], w1v = wrow[cin * 3 + 1], w2v = wrow[cin * 3 + 2];
            const float* xr = &ts[cin][0];
            float4 xa = *(const float4*)(xr + s0);
            float4 xb = *(const float4*)(xr + s0 + 4);
            float4 xc = *(const float4*)(xr + s0 + 8);
            float xv[12] = {xa.x, xa.y, xa.z, xa.w, xb.x, xb.y, xb.z, xb.w,
                            xc.x, xc.y, xc.z, xc.w};
#pragma unroll
            for (int j = 0; j < 8; j++) y[j] += xv[j] * w0 + xv[j + 1] * w1v + xv[j + 2] * w2v;
        }
        float* op = h2_pre + (size_t)(b * NN + n) * COUT * SS + cout * SS + s0;
        float4 o0 = {y[0], y[1], y[2], y[3]}, o1 = {y[4], y[5], y[6], y[7]};
        *(float4*)op = o0; *(float4*)(op + 4) = o1;
        float s = 0.f, q = 0.f;
#pragma unroll
        for (int j = 0; j < 8; j++) { s += y[j]; q += y[j] * y[j]; }
        s += __shfl_down(s, 1); s += __shfl_down(s, 2);
        q += __shfl_down(q, 1); q += __shfl_down(q, 2);
        accS += s; accQ += q;
    }
    if ((t & 3) == 0) {
        psum[cout * 512 + grp] = accS;
        pss[cout * 512 + grp] = accQ;
    }
}

// ---------- final: BN3+ReLU + residual 1x1 conv + ReLU, write [B,Cout,N,S] ----------
__global__ __launch_bounds__(256) void final_kernel(
    const float* __restrict__ x, const float* __restrict__ Wres,
    const float* __restrict__ bres, const float* __restrict__ h2_pre,
    const float* __restrict__ scale3, const float* __restrict__ shift3,
    float* __restrict__ out) {
    __shared__ __align__(16) float xs[CIN][36];
    __shared__ float wrl[COUT * 33];                // stride 33: conflict-free
    int t = threadIdx.x;
    int bn = blockIdx.x;
    int b = bn >> 10, n = bn & (NN - 1);
    {
        int cin = t >> 3, s4 = (t & 7) * 4;         // (cin*36+s4)%4==0: aligned
        *(float4*)&xs[cin][s4] =
            *(const float4*)(x + (((size_t)b * CIN + cin) * NN + n) * SS + s4);
    }
#pragma unroll
    for (int i = 0; i < 2; i++) {
        int lin = (i * 256 + t) * 4;                // rows of 32 (32%4==0)
        int cw = lin >> 5, c0 = lin & 31;
        float4 v = *(const float4*)(Wres + lin);
        float* dst = &wrl[cw * 33 + c0];
        dst[0] = v.x; dst[1] = v.y; dst[2] = v.z; dst[3] = v.w;
    }
    __syncthreads();
    int cout = t >> 2, s0 = (t & 3) * 8;
    float res[8];
    float bb = bres[cout];
#pragma unroll
    for (int j = 0; j < 8; j++) res[j] = bb;
    const float* wrow = &wrl[cout * 33];
#pragma unroll 4
    for (int cin = 0; cin < CIN; cin++) {
        float w = wrow[cin];
        float4 xa = *(const float4*)&xs[cin][s0];
        float4 xb = *(const float4*)&xs[cin][s0 + 4];
        res[0] += xa.x * w; res[1] += xa.y * w; res[2] += xa.z * w; res[3] += xa.w * w;
        res[4] += xb.x * w; res[5] += xb.y * w; res[6] += xb.z * w; res[7] += xb.w * w;
    }
    const float* hp = h2_pre + (size_t)bn * COUT * SS + cout * SS + s0;
    float4 h0 = *(const float4*)hp, h1 = *(const float4*)(hp + 4);
    float h2[8] = {h0.x, h0.y, h0.z, h0.w, h1.x, h1.y, h1.z, h1.w};
    float sc = scale3[cout], sh = shift3[cout];
    float o[8];
#pragma unroll
    for (int j = 0; j < 8; j++) {
        float hv = fmaxf(sc * h2[j] + sh, 0.f);
        o[j] = fmaxf(hv + res[j], 0.f);
    }
    float* op = out + (((size_t)b * COUT + cout) * NN + n) * SS + s0;
    float4 o0 = {o[0], o[1], o[2], o[3]}, o1 = {o[4], o[5], o[6], o[7]};
    *(float4*)op = o0; *(float4*)(op + 4) = o1;
}

// ---------- host ----------
extern "C" void kernel_launch(void* const* d_in, const int* in_sizes, int n_in,
                              void* d_out, int out_size, void* d_ws, size_t ws_size,
                              hipStream_t stream) {
    const float* x    = (const float*)d_in[0];
    const int*   ei   = (const int*)  d_in[1];
    const float* W1   = (const float*)d_in[2];
    const float* b1   = (const float*)d_in[3];
    const float* g1   = (const float*)d_in[4];
    const float* be1  = (const float*)d_in[5];
    const float* Wg   = (const float*)d_in[6];
    const float* bg   = (const float*)d_in[7];
    const float* gs   = (const float*)d_in[8];
    const float* bes  = (const float*)d_in[9];
    const float* W2   = (const float*)d_in[10];
    const float* b2   = (const float*)d_in[11];
    const float* g2   = (const float*)d_in[12];
    const float* be2  = (const float*)d_in[13];
    const float* Wres = (const float*)d_in[14];
    const float* bres = (const float*)d_in[15];
    float* out = (float*)d_out;
    int E = in_sizes[1] / 2;

    char* ws = (char*)d_ws;
    // zeroed region: [0, 73728)
    int*   deg    = (int*)  (ws + 0);            // 4096 B
    int*   cursor = (int*)  (ws + 4096);         // 4096 B
    float* sum2   = (float*)(ws + 8192);         // 32768 B
    float* ssq2   = (float*)(ws + 40960);        // 32768 B -> ends 73728
    int*   row_ptr= (int*)  (ws + 73728);        // 4100 B
    int*   flag   = (int*)  (ws + 77888);        // 4 B
    float* dinv   = (float*)(ws + 78080);        // 4096 B
    float* scale1 = (float*)(ws + 82176);        // 256 B each
    float* shift1 = (float*)(ws + 82432);
    float* scale3 = (float*)(ws + 82688);
    float* shift3 = (float*)(ws + 82944);
    float* scale2 = (float*)(ws + 83200);        // 32768 B
    float* shift2 = (float*)(ws + 115968);       // 32768 B -> 148736
    float* psum   = (float*)(ws + 148736);       // 131072 B (64 ch x 512 blk)
    float* pss    = (float*)(ws + 279808);       // 131072 B -> 410880
    int2*  edata  = (int2*) (ws + 410880);       // 8*E = 131072 B -> 541952
    float* bigA   = (float*)(ws + 542720);       // 33.55 MB: hw, then h2_pre
    // d_out doubles as scratch: h_pre (conv1 out), then agg (gcn out).
    float* h_pre  = out;
    float* agg    = out;

    hipMemsetAsync(ws, 0, 73728, stream);
    detect_kernel<<<1, 64, 0, stream>>>(ei, flag);
    int egrid = (E + 255) / 256;
    deg_count_kernel<<<egrid, 256, 0, stream>>>(ei, E, flag, deg);
    scan_kernel<<<1, NN, 0, stream>>>(deg, row_ptr, dinv);
    csr_fill_kernel<<<egrid, 256, 0, stream>>>(ei, E, flag, row_ptr, cursor, dinv, edata);

    conv1_kernel<<<512, 256, 0, stream>>>(x, W1, b1, h_pre, psum, pss);
    bn_reduce_kernel<<<64, 256, 0, stream>>>(psum, pss, g1, be1, scale1, shift1,
                                             1.f / (B_ * NN * SS));
    bn1_gemm_kernel<<<512, 256, 0, stream>>>(h_pre, scale1, shift1, Wg, bigA);
    gcn_kernel<<<B_ * SS * (NN / 32), 256, 0, stream>>>(bigA, row_ptr, edata, dinv, bg, agg,
                                                        sum2, ssq2);
    bn2_finalize_kernel<<<32, 256, 0, stream>>>(sum2, ssq2, gs, bes, scale2, shift2);
    conv2_kernel<<<512, 256, 0, stream>>>(agg, scale2, shift2, W2, b2, bigA, psum, pss);
    bn_reduce_kernel<<<64, 256, 0, stream>>>(psum, pss, g2, be2, scale3, shift3,
                                             1.f / (B_ * NN * SS));
    final_kernel<<<B_ * NN, 256, 0, stream>>>(x, Wres, bres, bigA, scale3, shift3, out);
}